// Round 3
// baseline (767.592 us; speedup 1.0000x reference)
//
#include <hip/hip_runtime.h>
#include <hip/hip_bf16.h>
#include <stdint.h>

typedef __attribute__((ext_vector_type(8))) short short8;
typedef __attribute__((ext_vector_type(4))) float floatx4;
typedef unsigned short u16;

#define MFMA16(a,b,c) __builtin_amdgcn_mfma_f32_16x16x32_bf16((a),(b),(c),0,0,0)

__device__ __forceinline__ u16 f2b(float f){
  unsigned int i; __builtin_memcpy(&i,&f,4); i += 0x7FFFu + ((i>>16)&1u); return (u16)(i>>16);
}
__device__ __forceinline__ int regid(int p){ return (p<56)?0:((p<60)?1:2); }

// LDS layout in u16 elements (bf16 working set):
//   QO : q[64][264]   (later reused as attention-output y[64][264])
//   KO : k[64][264]   (dead after Phase 3)
//   XVO: xw[64][264] -> vt[256][72]  (dead after Phase 3)
//   PO : per-wave softmax P buffers, 4 x [64][72]  (dead after Phase 3)
// Phase 4/5: oT f32 [256][72] (73728 B) overlays KO+XVO+PO (all dead).
#define QO 0
#define KO 16896
#define XVO 33792
#define PO 52224
#define LDS_ELEMS 70656   // *2B = 141312 bytes

__global__ void prep_w(const float* __restrict__ wqkv, const float* __restrict__ wo,
                       u16* __restrict__ wqkvT, u16* __restrict__ woT){
  int idx = blockIdx.x*256 + threadIdx.x;
  if(idx < 768*256){ int n = idx>>8, k = idx&255; wqkvT[idx] = f2b(wqkv[k*768 + n]); }
  else { int j = idx - 768*256; int n = j>>8, k = j&255; woT[j] = f2b(wo[k*256 + n]); }
}

__global__ __launch_bounds__(256,1) void swmsa_fused(
    const float* __restrict__ x, const u16* __restrict__ wqkvT, const float* __restrict__ bqkv,
    const u16* __restrict__ woT, const float* __restrict__ bo, const float* __restrict__ table,
    float* __restrict__ out)
{
  extern __shared__ u16 lds[];
  const int tid  = threadIdx.x;
  const int wave = tid>>6, lane = tid&63;
  const int quad = lane>>4, colid = lane&15;
  const int blk = blockIdx.x;
  const int b = blk>>6, win = blk&63, wy = win>>3, wx = win&7;
  const size_t imgbase = (size_t)b*256*4096;
  const int w0 = wx*8+4;
  const floatx4 fzero = {0.f,0.f,0.f,0.f};

  // ---- Phase 1: gather shifted-window tile, f32 -> bf16, xw[token][c] ----
  for(int i=0;i<8;++i){
    int rid = tid + 256*i;
    int c = rid>>3, ty = rid&7;
    int hs = (wy*8+ty+4)&63;
    const float* src = x + imgbase + (size_t)c*4096 + (size_t)hs*64;
    floatx4 lo, hi;
    if(wx<7){ lo = *(const floatx4*)(src+w0); hi = *(const floatx4*)(src+w0+4); }
    else    { lo = *(const floatx4*)(src+60); hi = *(const floatx4*)(src); }
    int t0 = ty*8;
    #pragma unroll
    for(int t=0;t<4;++t) lds[XVO + (t0+t)*264 + c]   = f2b(lo[t]);
    #pragma unroll
    for(int t=0;t<4;++t) lds[XVO + (t0+4+t)*264 + c] = f2b(hi[t]);
  }
  __syncthreads();

  // ---- Phase 2: qkv = xw @ w_qkv + b_qkv ----
  // wave w computes chunks {w, 4+w, 8+w}: q/k/v channels [64w,64w+64) == its own 2 heads
  for(int ci=0; ci<3; ++ci){
    const int col0 = (ci*4 + wave)*64;
    floatx4 acc[4][4];
    #pragma unroll
    for(int mt=0;mt<4;++mt)
      #pragma unroll
      for(int nt=0;nt<4;++nt) acc[mt][nt] = fzero;
    for(int k0=0;k0<256;k0+=32){
      short8 af[4], bfr[4];
      #pragma unroll
      for(int mt=0;mt<4;++mt) af[mt]  = *(const short8*)&lds[XVO + (mt*16+colid)*264 + k0 + quad*8];
      #pragma unroll
      for(int nt=0;nt<4;++nt) bfr[nt] = *(const short8*)&wqkvT[(size_t)(col0+nt*16+colid)*256 + k0 + quad*8];
      #pragma unroll
      for(int mt=0;mt<4;++mt)
        #pragma unroll
        for(int nt=0;nt<4;++nt) acc[mt][nt] = MFMA16(af[mt], bfr[nt], acc[mt][nt]);
    }
    if(ci==2) __syncthreads();   // all waves done reading xw before vt overwrites it
    #pragma unroll
    for(int nt=0;nt<4;++nt){
      int c = col0 + nt*16 + colid;
      float bias = bqkv[c];
      #pragma unroll
      for(int mt=0;mt<4;++mt)
        #pragma unroll
        for(int r=0;r<4;++r){
          int row = mt*16 + quad*4 + r;
          u16 bv = f2b(acc[mt][nt][r] + bias);
          if(ci==0)      lds[QO + row*264 + c] = bv;
          else if(ci==1) lds[KO + row*264 + (c-256)] = bv;
          else           lds[XVO + (c-512)*72 + row] = bv;   // v stored transposed
        }
    }
  }
  __syncthreads();

  // ---- Phase 3: attention, 2 heads per wave (all data wave-local) ----
  const float scale = 0.17677669529663687f;  // 32^-0.5
  u16* plds = lds + PO + wave*4608;
  for(int hi=0; hi<2; ++hi){
    const int h = wave*2 + hi;
    const int ch0 = h*32;
    floatx4 s[4][4];
    {
      short8 aq[4], bk[4];
      #pragma unroll
      for(int mt=0;mt<4;++mt) aq[mt] = *(const short8*)&lds[QO + (mt*16+colid)*264 + ch0 + quad*8];
      #pragma unroll
      for(int nt=0;nt<4;++nt) bk[nt] = *(const short8*)&lds[KO + (nt*16+colid)*264 + ch0 + quad*8];
      #pragma unroll
      for(int mt=0;mt<4;++mt)
        #pragma unroll
        for(int nt=0;nt<4;++nt) s[mt][nt] = MFMA16(aq[mt], bk[nt], fzero);
    }
    // rel-pos bias + shift mask
    int cntk[4], kys[4], kxs[4];
    #pragma unroll
    for(int nt=0;nt<4;++nt){
      int col = nt*16 + colid;
      kys[nt] = col>>3; kxs[nt] = col&7;
      cntk[nt] = regid(wy*8 + kys[nt])*3 + regid(wx*8 + kxs[nt]);
    }
    #pragma unroll
    for(int mt=0;mt<4;++mt)
      #pragma unroll
      for(int r=0;r<4;++r){
        int row = mt*16 + quad*4 + r;
        int ty = row>>3, tx = row&7;
        int cntq = regid(wy*8+ty)*3 + regid(wx*8+tx);
        #pragma unroll
        for(int nt=0;nt<4;++nt){
          int rel = (ty - kys[nt] + 7)*15 + (tx - kxs[nt] + 7);
          float add = table[rel*8 + h] + ((cntq==cntk[nt]) ? 0.f : -100.f);
          s[mt][nt][r] = s[mt][nt][r]*scale + add;
        }
      }
    __syncthreads();   // WAR: previous iteration's P reads complete
    // fp32 softmax over 64 keys
    #pragma unroll
    for(int mt=0;mt<4;++mt)
      #pragma unroll
      for(int r=0;r<4;++r){
        float mx = s[mt][0][r];
        #pragma unroll
        for(int nt=1;nt<4;++nt) mx = fmaxf(mx, s[mt][nt][r]);
        #pragma unroll
        for(int d=1; d<16; d<<=1) mx = fmaxf(mx, __shfl_xor(mx, d));
        float e[4], sum = 0.f;
        #pragma unroll
        for(int nt=0;nt<4;++nt){ e[nt] = __expf(s[mt][nt][r]-mx); sum += e[nt]; }
        #pragma unroll
        for(int d=1; d<16; d<<=1) sum += __shfl_xor(sum, d);
        float inv = 1.0f/sum;
        int row = mt*16 + quad*4 + r;
        #pragma unroll
        for(int nt=0;nt<4;++nt) plds[row*72 + nt*16 + colid] = f2b(e[nt]*inv);
      }
    __syncthreads();   // RAW: P visible (C-layout -> A-layout round trip)
    floatx4 o[4][2];
    #pragma unroll
    for(int mt=0;mt<4;++mt){ o[mt][0]=fzero; o[mt][1]=fzero; }
    #pragma unroll
    for(int k0=0;k0<64;k0+=32){
      short8 ap[4], bv[2];
      #pragma unroll
      for(int mt=0;mt<4;++mt) ap[mt] = *(const short8*)&plds[(mt*16+colid)*72 + k0 + quad*8];
      #pragma unroll
      for(int n2=0;n2<2;++n2) bv[n2] = *(const short8*)&lds[XVO + (ch0 + n2*16 + colid)*72 + k0 + quad*8];
      #pragma unroll
      for(int mt=0;mt<4;++mt)
        #pragma unroll
        for(int n2=0;n2<2;++n2) o[mt][n2] = MFMA16(ap[mt], bv[n2], o[mt][n2]);
    }
    // write head output into dead q columns (y == Q region, wave-local cols)
    #pragma unroll
    for(int n2=0;n2<2;++n2){
      int c = ch0 + n2*16 + colid;
      #pragma unroll
      for(int mt=0;mt<4;++mt)
        #pragma unroll
        for(int r=0;r<4;++r){
          int row = mt*16 + quad*4 + r;
          lds[QO + row*264 + c] = f2b(o[mt][n2][r]);
        }
    }
  }
  __syncthreads();   // y complete for all waves; KO/XVO/PO now dead

  // ---- Phase 4: out = y @ w_o + b_o, staged f32 transposed over dead K/vt/P ----
  float* oT = (float*)(lds + KO);   // f32 [256][72] = 73728 B
  {
    const int col0 = wave*64;
    floatx4 acc[4][4];
    #pragma unroll
    for(int mt=0;mt<4;++mt)
      #pragma unroll
      for(int nt=0;nt<4;++nt) acc[mt][nt] = fzero;
    for(int k0=0;k0<256;k0+=32){
      short8 ay[4], bw[4];
      #pragma unroll
      for(int mt=0;mt<4;++mt) ay[mt] = *(const short8*)&lds[QO + (mt*16+colid)*264 + k0 + quad*8];
      #pragma unroll
      for(int nt=0;nt<4;++nt) bw[nt] = *(const short8*)&woT[(size_t)(col0+nt*16+colid)*256 + k0 + quad*8];
      #pragma unroll
      for(int mt=0;mt<4;++mt)
        #pragma unroll
        for(int nt=0;nt<4;++nt) acc[mt][nt] = MFMA16(ay[mt], bw[nt], acc[mt][nt]);
    }
    #pragma unroll
    for(int nt=0;nt<4;++nt){
      int c = col0 + nt*16 + colid;
      float bias = bo[c];
      #pragma unroll
      for(int mt=0;mt<4;++mt)
        #pragma unroll
        for(int r=0;r<4;++r){
          int row = mt*16 + quad*4 + r;
          oT[c*72 + row] = acc[mt][nt][r] + bias;   // oT[ch][token], f32
        }
    }
  }
  __syncthreads();

  // ---- Phase 5: scatter with window-reverse + inverse roll (f32) ----
  for(int i=0;i<8;++i){
    int rid = tid + 256*i;
    int c = rid>>3, ty = rid&7;
    floatx4 lo = *(const floatx4*)&oT[c*72 + ty*8];
    floatx4 hi = *(const floatx4*)&oT[c*72 + ty*8 + 4];
    int hd = (wy*8+ty+4)&63;
    float* dst = out + imgbase + (size_t)c*4096 + (size_t)hd*64;
    if(wx<7){ *(floatx4*)(dst+w0) = lo; *(floatx4*)(dst+w0+4) = hi; }
    else    { *(floatx4*)(dst+60) = lo; *(floatx4*)(dst)      = hi; }
  }
}

extern "C" void kernel_launch(void* const* d_in, const int* in_sizes, int n_in,
                              void* d_out, int out_size, void* d_ws, size_t ws_size,
                              hipStream_t stream) {
  const float* x     = (const float*)d_in[0];
  const float* wqkv  = (const float*)d_in[1];
  const float* bqkv  = (const float*)d_in[2];
  const float* wo    = (const float*)d_in[3];
  const float* bo    = (const float*)d_in[4];
  const float* table = (const float*)d_in[5];
  float* out = (float*)d_out;

  u16* wqkvT = (u16*)d_ws;            // 768x256 bf16
  u16* woT   = wqkvT + 768*256;       // 256x256 bf16  (total ws use: 524288 B)

  prep_w<<<1024, 256, 0, stream>>>(wqkv, wo, wqkvT, woT);

  (void)hipFuncSetAttribute((const void*)swmsa_fused,
                            hipFuncAttributeMaxDynamicSharedMemorySize, LDS_ELEMS*2);
  swmsa_fused<<<2048, 256, LDS_ELEMS*2, stream>>>(x, wqkvT, bqkv, woT, bo, table, out);
}

// Round 4
// 501.072 us; speedup vs baseline: 1.5319x; 1.5319x over previous
//
#include <hip/hip_runtime.h>
#include <stdint.h>

typedef __attribute__((ext_vector_type(8))) short short8;
typedef __attribute__((ext_vector_type(4))) float floatx4;
typedef unsigned short u16;

#define MFMA16(a,b,c) __builtin_amdgcn_mfma_f32_16x16x32_bf16((a),(b),(c),0,0,0)

__device__ __forceinline__ u16 f2b(float f){
  unsigned int i; __builtin_memcpy(&i,&f,4); i += 0x7FFFu + ((i>>16)&1u); return (u16)(i>>16);
}
__device__ __forceinline__ int regid(int p){ return (p<56)?0:((p<60)?1:2); }

// LDS layout (u16 elems), total 35328 elems = 70656 B  -> 2 blocks/CU:
//   XW : xw[64][264]  (phase 1-2)  -> y[64][264] (phase 3-4)        16896 elems
//   SC : per-wave scratch [64][72] x4 (q/k/v/P round-trips, serial) 18432 elems
//        phase 4/5: oT-half f32[128][72] (36864 B) overlays SC
#define SCO 16896
#define LDS_ELEMS 35328

__global__ void prep_w(const float* __restrict__ wqkv, const float* __restrict__ wo,
                       u16* __restrict__ wqkvT, u16* __restrict__ woT){
  int idx = blockIdx.x*256 + threadIdx.x;
  if(idx < 768*256){ int n = idx>>8, k = idx&255; wqkvT[idx] = f2b(wqkv[k*768 + n]); }
  else { int j = idx - 768*256; int n = j>>8, k = j&255; woT[j] = f2b(wo[k*256 + n]); }
}

__global__ __launch_bounds__(256,2) void swmsa_fused(
    const float* __restrict__ x, const u16* __restrict__ wqkvT, const float* __restrict__ bqkv,
    const u16* __restrict__ woT, const float* __restrict__ bo, const float* __restrict__ table,
    float* __restrict__ out)
{
  extern __shared__ u16 lds[];
  const int tid  = threadIdx.x;
  const int wave = tid>>6, lane = tid&63;
  const int quad = lane>>4, colid = lane&15;
  const int blk = blockIdx.x;
  const int b = blk>>6, win = blk&63, wy = win>>3, wx = win&7;
  const size_t imgbase = (size_t)b*256*4096;
  const int w0 = wx*8+4;
  const floatx4 fzero = {0.f,0.f,0.f,0.f};
  u16* sc = lds + SCO + wave*4608;

  // ---- Phase 1: gather shifted window, f32->bf16, transpose-pack, xw[tok][ch] ----
  for(int i=0;i<2;++i){
    int unit = tid + 256*i;
    int cg = unit>>3, ty = unit&7;
    int hs = (wy*8+ty+4)&63;
    u16 vv[4][8];
    #pragma unroll
    for(int cc=0;cc<4;++cc){
      const float* src = x + imgbase + (size_t)(cg*4+cc)*4096 + (size_t)hs*64;
      floatx4 lo, hi;
      if(wx<7){ lo = *(const floatx4*)(src+w0); hi = *(const floatx4*)(src+w0+4); }
      else    { lo = *(const floatx4*)(src+60); hi = *(const floatx4*)(src); }
      #pragma unroll
      for(int t=0;t<4;++t){ vv[cc][t]=f2b(lo[t]); vv[cc][4+t]=f2b(hi[t]); }
    }
    #pragma unroll
    for(int t=0;t<8;++t){
      uint64_t pk = (uint64_t)vv[0][t] | ((uint64_t)vv[1][t]<<16)
                  | ((uint64_t)vv[2][t]<<32) | ((uint64_t)vv[3][t]<<48);
      *(uint64_t*)&lds[(ty*8+t)*264 + cg*4] = pk;
    }
  }
  __syncthreads();

  // ---- Phase 2: qkv = xw @ w_qkv + b_qkv; frags -> registers via wave-private scratch ----
  short8 aq2[2][4], bk2[2][4], bv2[2][2][2];
  for(int ci=0; ci<3; ++ci){
    const int col0 = (ci*4 + wave)*64;
    floatx4 acc[4][4];
    #pragma unroll
    for(int mt=0;mt<4;++mt)
      #pragma unroll
      for(int nt=0;nt<4;++nt) acc[mt][nt] = fzero;
    for(int k0=0;k0<256;k0+=32){
      short8 af[4], bfr[4];
      #pragma unroll
      for(int mt=0;mt<4;++mt) af[mt]  = *(const short8*)&lds[(mt*16+colid)*264 + k0 + quad*8];
      #pragma unroll
      for(int nt=0;nt<4;++nt) bfr[nt] = *(const short8*)&wqkvT[(size_t)(col0+nt*16+colid)*256 + k0 + quad*8];
      #pragma unroll
      for(int mt=0;mt<4;++mt)
        #pragma unroll
        for(int nt=0;nt<4;++nt) acc[mt][nt] = MFMA16(af[mt], bfr[nt], acc[mt][nt]);
    }
    // epilogue into wave-private scratch (q/k: C-layout; v: transposed)
    #pragma unroll
    for(int nt=0;nt<4;++nt){
      int cloc = nt*16 + colid;
      float bias = bqkv[col0 + cloc];
      #pragma unroll
      for(int mt=0;mt<4;++mt)
        #pragma unroll
        for(int r=0;r<4;++r){
          int row = mt*16 + quad*4 + r;
          u16 bvv = f2b(acc[mt][nt][r] + bias);
          if(ci<2) sc[row*72 + cloc] = bvv;
          else     sc[cloc*72 + row] = bvv;   // vt[ch][tok]
        }
    }
    // read back fragments (wave-private; DS in-order + lgkmcnt)
    if(ci==0){
      #pragma unroll
      for(int hi=0;hi<2;++hi)
        #pragma unroll
        for(int mt=0;mt<4;++mt)
          aq2[hi][mt] = *(const short8*)&sc[(mt*16+colid)*72 + hi*32 + quad*8];
    } else if(ci==1){
      #pragma unroll
      for(int hi=0;hi<2;++hi)
        #pragma unroll
        for(int mt=0;mt<4;++mt)
          bk2[hi][mt] = *(const short8*)&sc[(mt*16+colid)*72 + hi*32 + quad*8];
    } else {
      #pragma unroll
      for(int hi=0;hi<2;++hi)
        #pragma unroll
        for(int n2=0;n2<2;++n2)
          #pragma unroll
          for(int kc=0;kc<2;++kc)
            bv2[hi][n2][kc] = *(const short8*)&sc[(hi*32+n2*16+colid)*72 + kc*32 + quad*8];
    }
  }
  __syncthreads();   // all waves done reading xw; XW becomes y

  // ---- Phase 3: attention, 2 heads/wave, barrier-free (all wave-private) ----
  const float scale = 0.17677669529663687f;  // 32^-0.5
  #pragma unroll
  for(int hi=0; hi<2; ++hi){
    const int h = wave*2 + hi;
    floatx4 s[4][4];
    #pragma unroll
    for(int mt=0;mt<4;++mt)
      #pragma unroll
      for(int nt=0;nt<4;++nt) s[mt][nt] = MFMA16(aq2[hi][mt], bk2[hi][nt], fzero);
    int cntk[4], kys[4], kxs[4];
    #pragma unroll
    for(int nt=0;nt<4;++nt){
      int col = nt*16 + colid;
      kys[nt] = col>>3; kxs[nt] = col&7;
      cntk[nt] = regid(wy*8 + kys[nt])*3 + regid(wx*8 + kxs[nt]);
    }
    #pragma unroll
    for(int mt=0;mt<4;++mt)
      #pragma unroll
      for(int r=0;r<4;++r){
        int row = mt*16 + quad*4 + r;
        int ty = row>>3, tx = row&7;
        int cntq = regid(wy*8+ty)*3 + regid(wx*8+tx);
        #pragma unroll
        for(int nt=0;nt<4;++nt){
          int rel = (ty - kys[nt] + 7)*15 + (tx - kxs[nt] + 7);
          float add = table[rel*8 + h] + ((cntq==cntk[nt]) ? 0.f : -100.f);
          s[mt][nt][r] = s[mt][nt][r]*scale + add;
        }
      }
    // fp32 softmax over 64 keys (16-lane groups x 4 tiles)
    #pragma unroll
    for(int mt=0;mt<4;++mt)
      #pragma unroll
      for(int r=0;r<4;++r){
        float mx = s[mt][0][r];
        #pragma unroll
        for(int nt=1;nt<4;++nt) mx = fmaxf(mx, s[mt][nt][r]);
        #pragma unroll
        for(int d=1; d<16; d<<=1) mx = fmaxf(mx, __shfl_xor(mx, d));
        float e[4], sum = 0.f;
        #pragma unroll
        for(int nt=0;nt<4;++nt){ e[nt] = __expf(s[mt][nt][r]-mx); sum += e[nt]; }
        #pragma unroll
        for(int d=1; d<16; d<<=1) sum += __shfl_xor(sum, d);
        float inv = 1.0f/sum;
        int row = mt*16 + quad*4 + r;
        #pragma unroll
        for(int nt=0;nt<4;++nt) sc[row*72 + nt*16 + colid] = f2b(e[nt]*inv);
      }
    // PV (P round-trip is wave-private)
    floatx4 o[4][2];
    #pragma unroll
    for(int mt=0;mt<4;++mt){ o[mt][0]=fzero; o[mt][1]=fzero; }
    #pragma unroll
    for(int kc=0;kc<2;++kc){
      short8 ap[4];
      #pragma unroll
      for(int mt=0;mt<4;++mt) ap[mt] = *(const short8*)&sc[(mt*16+colid)*72 + kc*32 + quad*8];
      #pragma unroll
      for(int mt=0;mt<4;++mt)
        #pragma unroll
        for(int n2=0;n2<2;++n2) o[mt][n2] = MFMA16(ap[mt], bv2[hi][n2][kc], o[mt][n2]);
    }
    // y into XW (wave-own columns)
    #pragma unroll
    for(int n2=0;n2<2;++n2){
      int c = h*32 + n2*16 + colid;
      #pragma unroll
      for(int mt=0;mt<4;++mt)
        #pragma unroll
        for(int r=0;r<4;++r){
          int row = mt*16 + quad*4 + r;
          lds[row*264 + c] = f2b(o[mt][n2][r]);
        }
    }
  }
  __syncthreads();   // y complete; SC free for oT halves

  // ---- Phase 4+5: out = y @ w_o + b_o in two 128-channel halves ----
  float* oTh = (float*)(lds + SCO);   // f32 [128][72] = 36864 B
  for(int np=0; np<2; ++np){
    const int col0 = np*128 + wave*32;
    floatx4 acc[4][2];
    #pragma unroll
    for(int mt=0;mt<4;++mt){ acc[mt][0]=fzero; acc[mt][1]=fzero; }
    for(int k0=0;k0<256;k0+=32){
      short8 ay[4], bw[2];
      #pragma unroll
      for(int mt=0;mt<4;++mt) ay[mt] = *(const short8*)&lds[(mt*16+colid)*264 + k0 + quad*8];
      #pragma unroll
      for(int n2=0;n2<2;++n2) bw[n2] = *(const short8*)&woT[(size_t)(col0+n2*16+colid)*256 + k0 + quad*8];
      #pragma unroll
      for(int mt=0;mt<4;++mt)
        #pragma unroll
        for(int n2=0;n2<2;++n2) acc[mt][n2] = MFMA16(ay[mt], bw[n2], acc[mt][n2]);
    }
    #pragma unroll
    for(int n2=0;n2<2;++n2){
      int cl = wave*32 + n2*16 + colid;
      float bias = bo[np*128 + cl];
      #pragma unroll
      for(int mt=0;mt<4;++mt)
        #pragma unroll
        for(int r=0;r<4;++r)
          oTh[cl*72 + mt*16 + quad*4 + r] = acc[mt][n2][r] + bias;
    }
    __syncthreads();   // oT half visible
    for(int i=0;i<4;++i){
      int rid = tid + 256*i;
      int cl = rid>>3, ty = rid&7;
      floatx4 lo  = *(const floatx4*)&oTh[cl*72 + ty*8];
      floatx4 hi2 = *(const floatx4*)&oTh[cl*72 + ty*8 + 4];
      int hd = (wy*8+ty+4)&63;
      float* dst = out + imgbase + (size_t)(np*128+cl)*4096 + (size_t)hd*64;
      if(wx<7){ *(floatx4*)(dst+w0) = lo; *(floatx4*)(dst+w0+4) = hi2; }
      else    { *(floatx4*)(dst+60) = lo; *(floatx4*)(dst)      = hi2; }
    }
    if(np==0) __syncthreads();   // WAR: scatter done before next half's epilogue
  }
}

extern "C" void kernel_launch(void* const* d_in, const int* in_sizes, int n_in,
                              void* d_out, int out_size, void* d_ws, size_t ws_size,
                              hipStream_t stream) {
  const float* x     = (const float*)d_in[0];
  const float* wqkv  = (const float*)d_in[1];
  const float* bqkv  = (const float*)d_in[2];
  const float* wo    = (const float*)d_in[3];
  const float* bo    = (const float*)d_in[4];
  const float* table = (const float*)d_in[5];
  float* out = (float*)d_out;

  u16* wqkvT = (u16*)d_ws;            // 768x256 bf16
  u16* woT   = wqkvT + 768*256;       // 256x256 bf16

  prep_w<<<1024, 256, 0, stream>>>(wqkv, wo, wqkvT, woT);

  (void)hipFuncSetAttribute((const void*)swmsa_fused,
                            hipFuncAttributeMaxDynamicSharedMemorySize, LDS_ELEMS*2);
  swmsa_fused<<<2048, 256, LDS_ELEMS*2, stream>>>(x, wqkvT, bqkv, woT, bo, table, out);
}

// Round 5
// 484.327 us; speedup vs baseline: 1.5849x; 1.0346x over previous
//
#include <hip/hip_runtime.h>
#include <stdint.h>

typedef __attribute__((ext_vector_type(8))) short short8;
typedef __attribute__((ext_vector_type(4))) float floatx4;
typedef unsigned short u16;
typedef unsigned int u32;

#define MFMA16(a,b,c) __builtin_amdgcn_mfma_f32_16x16x32_bf16((a),(b),(c),0,0,0)

__device__ __forceinline__ u16 f2b(float f){
  u32 i; __builtin_memcpy(&i,&f,4); i += 0x7FFFu + ((i>>16)&1u); return (u16)(i>>16);
}
__device__ __forceinline__ int regid(int p){ return (p<56)?0:((p<60)?1:2); }

// LDS (u16 elems), total 26112 elems = 52224 B -> 3 blocks/CU:
//   XW : xw[64][264] (phase 1-2) -> y[64][264] (phase 3-4)       16896 elems
//   SC : per-wave scratch [64][36] x4 -- q/k/P in 32-col halves,
//        v as [32ch][72tok] halves                                9216 elems
//        phase 4: oQ f32[64][72] (18432 B) overlays whole SC
#define SCO 16896
#define LDS_ELEMS 26112

__global__ void prep_w(const float* __restrict__ wqkv, const float* __restrict__ wo,
                       u16* __restrict__ wqkvT, u16* __restrict__ woT){
  int idx = blockIdx.x*256 + threadIdx.x;
  if(idx < 768*256){ int n = idx>>8, k = idx&255; wqkvT[idx] = f2b(wqkv[k*768 + n]); }
  else { int j = idx - 768*256; int n = j>>8, k = j&255; woT[j] = f2b(wo[k*256 + n]); }
}

__global__ __launch_bounds__(256,3) void swmsa_fused(
    const float* __restrict__ x, const u16* __restrict__ wqkvT, const float* __restrict__ bqkv,
    const u16* __restrict__ woT, const float* __restrict__ bo, const float* __restrict__ table,
    float* __restrict__ out)
{
  extern __shared__ u16 lds[];
  const int tid  = threadIdx.x;
  const int wave = tid>>6, lane = tid&63;
  const int quad = lane>>4, colid = lane&15;
  // XCD swizzle: 8 windows of one image-row run consecutively on one XCD
  const int bi = blockIdx.x;
  const int xcd = bi & 7, j = bi >> 3;
  const int r0 = ((j >> 3) << 3) | xcd;   // row id = b*8+wy, 0..255
  const int wx = j & 7;
  const int b = r0 >> 3, wy = r0 & 7;
  const size_t imgbase = (size_t)b*256*4096;
  const int w0 = wx*8+4;
  const floatx4 fzero = {0.f,0.f,0.f,0.f};
  u16* sc = lds + SCO + wave*2304;

  // ---- Phase 1: gather shifted window, f32->bf16, transpose-pack, xw[tok][ch] ----
  for(int i=0;i<2;++i){
    int unit = tid + 256*i;
    int cg = unit>>3, ty = unit&7;
    int hs = (wy*8+ty+4)&63;
    u16 vv[4][8];
    #pragma unroll
    for(int cc=0;cc<4;++cc){
      const float* src = x + imgbase + (size_t)(cg*4+cc)*4096 + (size_t)hs*64;
      floatx4 lo, hi;
      if(wx<7){ lo = *(const floatx4*)(src+w0); hi = *(const floatx4*)(src+w0+4); }
      else    { lo = *(const floatx4*)(src+60); hi = *(const floatx4*)(src); }
      #pragma unroll
      for(int t=0;t<4;++t){ vv[cc][t]=f2b(lo[t]); vv[cc][4+t]=f2b(hi[t]); }
    }
    #pragma unroll
    for(int t=0;t<8;++t){
      uint64_t pk = (uint64_t)vv[0][t] | ((uint64_t)vv[1][t]<<16)
                  | ((uint64_t)vv[2][t]<<32) | ((uint64_t)vv[3][t]<<48);
      *(uint64_t*)&lds[(ty*8+t)*264 + cg*4] = pk;
    }
  }
  __syncthreads();

  // ---- Phase 2: qkv = xw @ w_qkv + b_qkv; frags -> regs via 32-col half round trips ----
  short8 aq2[2][4], bk2[2][4], bv2[2][2][2];
  for(int t3=0; t3<3; ++t3){
    const int cc = 2 - t3;                    // v, k, q (q last: short aq2 lifetime)
    const int col0 = (cc*4 + wave)*64;
    floatx4 acc[4][4];
    #pragma unroll
    for(int mt=0;mt<4;++mt)
      #pragma unroll
      for(int nt=0;nt<4;++nt) acc[mt][nt] = fzero;
    for(int k0=0;k0<256;k0+=32){
      short8 af[4], bfr[4];
      #pragma unroll
      for(int mt=0;mt<4;++mt) af[mt]  = *(const short8*)&lds[(mt*16+colid)*264 + k0 + quad*8];
      #pragma unroll
      for(int nt=0;nt<4;++nt) bfr[nt] = *(const short8*)&wqkvT[(size_t)(col0+nt*16+colid)*256 + k0 + quad*8];
      #pragma unroll
      for(int mt=0;mt<4;++mt)
        #pragma unroll
        for(int nt=0;nt<4;++nt) acc[mt][nt] = MFMA16(af[mt], bfr[nt], acc[mt][nt]);
    }
    // epilogue in two 32-col halves through wave-private scratch
    #pragma unroll
    for(int hf=0; hf<2; ++hf){
      #pragma unroll
      for(int nt2=0; nt2<2; ++nt2){
        int nt = hf*2 + nt2;
        float bias = bqkv[col0 + nt*16 + colid];
        #pragma unroll
        for(int mt=0;mt<4;++mt)
          #pragma unroll
          for(int rr=0;rr<4;++rr){
            int row = mt*16 + quad*4 + rr;
            u16 bvv = f2b(acc[mt][nt][rr] + bias);
            if(cc==2) sc[(nt2*16+colid)*72 + row] = bvv;     // vt[ch_local][tok]
            else      sc[row*36 + nt2*16 + colid] = bvv;     // [tok][ch_local]
          }
      }
      if(cc==2){
        #pragma unroll
        for(int n2=0;n2<2;++n2)
          #pragma unroll
          for(int kc=0;kc<2;++kc)
            bv2[hf][n2][kc] = *(const short8*)&sc[(n2*16+colid)*72 + kc*32 + quad*8];
      } else if(cc==1){
        #pragma unroll
        for(int mt=0;mt<4;++mt) bk2[hf][mt] = *(const short8*)&sc[(mt*16+colid)*36 + quad*8];
      } else {
        #pragma unroll
        for(int mt=0;mt<4;++mt) aq2[hf][mt] = *(const short8*)&sc[(mt*16+colid)*36 + quad*8];
      }
    }
  }
  __syncthreads();   // all waves done with xw; XW becomes y

  // ---- Phase 3: attention, 2 heads/wave, barrier-free ----
  const float scale = 0.17677669529663687f;  // 32^-0.5
  #pragma unroll
  for(int hi=0; hi<2; ++hi){
    const int h = wave*2 + hi;
    floatx4 s[4][4];
    #pragma unroll
    for(int mt=0;mt<4;++mt)
      #pragma unroll
      for(int nt=0;nt<4;++nt) s[mt][nt] = MFMA16(aq2[hi][mt], bk2[hi][nt], fzero);
    int cntk[4], kys[4], kxs[4];
    #pragma unroll
    for(int nt=0;nt<4;++nt){
      int col = nt*16 + colid;
      kys[nt] = col>>3; kxs[nt] = col&7;
      cntk[nt] = regid(wy*8 + kys[nt])*3 + regid(wx*8 + kxs[nt]);
    }
    #pragma unroll
    for(int mt=0;mt<4;++mt)
      #pragma unroll
      for(int rr=0;rr<4;++rr){
        int row = mt*16 + quad*4 + rr;
        int ty = row>>3, tx = row&7;
        int cntq = regid(wy*8+ty)*3 + regid(wx*8+tx);
        #pragma unroll
        for(int nt=0;nt<4;++nt){
          int rel = (ty - kys[nt] + 7)*15 + (tx - kxs[nt] + 7);
          float add = table[rel*8 + h] + ((cntq==cntk[nt]) ? 0.f : -100.f);
          s[mt][nt][rr] = s[mt][nt][rr]*scale + add;
        }
      }
    // softmax; write keys 0-31 to scratch, park keys 32-63 packed-bf16 in regs
    u32 gpk[4][4];
    #pragma unroll
    for(int mt=0;mt<4;++mt)
      #pragma unroll
      for(int rr=0;rr<4;++rr){
        float mx = s[mt][0][rr];
        #pragma unroll
        for(int nt=1;nt<4;++nt) mx = fmaxf(mx, s[mt][nt][rr]);
        #pragma unroll
        for(int d=1; d<16; d<<=1) mx = fmaxf(mx, __shfl_xor(mx, d));
        float e[4], sum = 0.f;
        #pragma unroll
        for(int nt=0;nt<4;++nt){ e[nt] = __expf(s[mt][nt][rr]-mx); sum += e[nt]; }
        #pragma unroll
        for(int d=1; d<16; d<<=1) sum += __shfl_xor(sum, d);
        float inv = 1.0f/sum;
        int row = mt*16 + quad*4 + rr;
        sc[row*36 + colid]      = f2b(e[0]*inv);
        sc[row*36 + 16 + colid] = f2b(e[1]*inv);
        gpk[mt][rr] = (u32)f2b(e[2]*inv) | ((u32)f2b(e[3]*inv) << 16);
      }
    floatx4 o[4][2];
    #pragma unroll
    for(int mt=0;mt<4;++mt){ o[mt][0]=fzero; o[mt][1]=fzero; }
    #pragma unroll
    for(int kc=0;kc<2;++kc){
      if(kc==1){
        #pragma unroll
        for(int mt=0;mt<4;++mt)
          #pragma unroll
          for(int rr=0;rr<4;++rr){
            int row = mt*16 + quad*4 + rr;
            sc[row*36 + colid]      = (u16)(gpk[mt][rr] & 0xffffu);
            sc[row*36 + 16 + colid] = (u16)(gpk[mt][rr] >> 16);
          }
      }
      short8 ap[4];
      #pragma unroll
      for(int mt=0;mt<4;++mt) ap[mt] = *(const short8*)&sc[(mt*16+colid)*36 + quad*8];
      #pragma unroll
      for(int mt=0;mt<4;++mt)
        #pragma unroll
        for(int n2=0;n2<2;++n2) o[mt][n2] = MFMA16(ap[mt], bv2[hi][n2][kc], o[mt][n2]);
    }
    // y into XW (wave-own columns)
    #pragma unroll
    for(int n2=0;n2<2;++n2){
      int c = h*32 + n2*16 + colid;
      #pragma unroll
      for(int mt=0;mt<4;++mt)
        #pragma unroll
        for(int rr=0;rr<4;++rr)
          lds[(mt*16+quad*4+rr)*264 + c] = f2b(o[mt][n2][rr]);
    }
  }
  __syncthreads();   // y complete; SC region free for oQ

  // ---- Phase 4+5: out = y @ w_o + b_o in four 64-channel quarters ----
  float* oQ = (float*)(lds + SCO);   // f32 [64][72] = 18432 B
  for(int np=0; np<4; ++np){
    const int col0 = np*64 + wave*16;
    floatx4 acc[4];
    #pragma unroll
    for(int mt=0;mt<4;++mt) acc[mt] = fzero;
    for(int k0=0;k0<256;k0+=32){
      short8 ay[4], bw;
      #pragma unroll
      for(int mt=0;mt<4;++mt) ay[mt] = *(const short8*)&lds[(mt*16+colid)*264 + k0 + quad*8];
      bw = *(const short8*)&woT[(size_t)(col0+colid)*256 + k0 + quad*8];
      #pragma unroll
      for(int mt=0;mt<4;++mt) acc[mt] = MFMA16(ay[mt], bw, acc[mt]);
    }
    if(np) __syncthreads();   // WAR: previous quarter's scatter reads done
    {
      float bias = bo[col0 + colid];
      int cl = wave*16 + colid;
      #pragma unroll
      for(int mt=0;mt<4;++mt)
        #pragma unroll
        for(int rr=0;rr<4;++rr)
          oQ[cl*72 + mt*16 + quad*4 + rr] = acc[mt][rr] + bias;
    }
    __syncthreads();   // oQ quarter visible
    #pragma unroll
    for(int i=0;i<2;++i){
      int unit = tid + 256*i;
      int cl = unit>>3, ty = unit&7;
      floatx4 lo  = *(const floatx4*)&oQ[cl*72 + ty*8];
      floatx4 hi2 = *(const floatx4*)&oQ[cl*72 + ty*8 + 4];
      int hd = (wy*8+ty+4)&63;
      float* dst = out + imgbase + (size_t)(np*64+cl)*4096 + (size_t)hd*64;
      if(wx<7){ *(floatx4*)(dst+w0) = lo; *(floatx4*)(dst+w0+4) = hi2; }
      else    { *(floatx4*)(dst+60) = lo; *(floatx4*)(dst)      = hi2; }
    }
  }
}

extern "C" void kernel_launch(void* const* d_in, const int* in_sizes, int n_in,
                              void* d_out, int out_size, void* d_ws, size_t ws_size,
                              hipStream_t stream) {
  const float* x     = (const float*)d_in[0];
  const float* wqkv  = (const float*)d_in[1];
  const float* bqkv  = (const float*)d_in[2];
  const float* wo    = (const float*)d_in[3];
  const float* bo    = (const float*)d_in[4];
  const float* table = (const float*)d_in[5];
  float* out = (float*)d_out;

  u16* wqkvT = (u16*)d_ws;            // 768x256 bf16
  u16* woT   = wqkvT + 768*256;       // 256x256 bf16

  prep_w<<<1024, 256, 0, stream>>>(wqkv, wo, wqkvT, woT);

  (void)hipFuncSetAttribute((const void*)swmsa_fused,
                            hipFuncAttributeMaxDynamicSharedMemorySize, LDS_ELEMS*2);
  swmsa_fused<<<2048, 256, LDS_ELEMS*2, stream>>>(x, wqkvT, bqkv, woT, bo, table, out);
}